// Round 2
// baseline (157.915 us; speedup 1.0000x reference)
//
#include <hip/hip_runtime.h>
#include <math.h>

#define EPSF 1e-8f

// Analytic eigenvalues of symmetric 3x3 (trigonometric/Cardano), fp64 for
// robustness near degenerate eigenvalues; returns sum(sqrt(clip(eig, 1e-8))).
__device__ __forceinline__ double tr_sqrt_eig(double a00, double a11, double a22,
                                              double a01, double a02, double a12)
{
    double q = (a00 + a11 + a22) * (1.0 / 3.0);
    double b00 = a00 - q, b11 = a11 - q, b22 = a22 - q;
    double p1 = a01 * a01 + a02 * a02 + a12 * a12;
    double p2 = b00 * b00 + b11 * b11 + b22 * b22 + 2.0 * p1;

    double e0, e1, e2;
    if (p2 <= 1e-30) {
        e0 = q; e1 = q; e2 = q;
    } else {
        double p = sqrt(p2 * (1.0 / 6.0));
        double invp = 1.0 / p;
        double c00 = b00 * invp, c11 = b11 * invp, c22 = b22 * invp;
        double c01 = a01 * invp, c02 = a02 * invp, c12 = a12 * invp;
        double detB = c00 * (c11 * c22 - c12 * c12)
                    - c01 * (c01 * c22 - c12 * c02)
                    + c02 * (c01 * c12 - c11 * c02);
        double r = 0.5 * detB;
        r = fmin(1.0, fmax(-1.0, r));
        double phi = acos(r) * (1.0 / 3.0);
        double twop = 2.0 * p;
        e0 = q + twop * cos(phi);
        e2 = q + twop * cos(phi + 2.0943951023931953);  // + 2*pi/3
        e1 = 3.0 * q - e0 - e2;
    }
    double eps_d = 1e-8;
    return sqrt(fmax(e0, eps_d)) + sqrt(fmax(e1, eps_d)) + sqrt(fmax(e2, eps_d));
}

// 4 Gaussians per thread: all global accesses become aligned float4
// (loc/scale: 3 x float4 per thread, rot: 9 x float4, out: 1 x float4).
__global__ __launch_bounds__(256) void wasserstein_kernel(
    const float* __restrict__ loc1, const float* __restrict__ scale1,
    const float* __restrict__ rot1, const float* __restrict__ loc2,
    const float* __restrict__ scale2, const float* __restrict__ rot2,
    float* __restrict__ out, int B4)
{
    int t = blockIdx.x * blockDim.x + threadIdx.x;
    if (t >= B4) return;

    const float4* l1p = (const float4*)loc1   + 3 * t;
    const float4* l2p = (const float4*)loc2   + 3 * t;
    const float4* s1p = (const float4*)scale1 + 3 * t;
    const float4* s2p = (const float4*)scale2 + 3 * t;
    const float4* r1p = (const float4*)rot1   + 9 * t;
    const float4* r2p = (const float4*)rot2   + 9 * t;

    // ---- Phase A: location difference (frees 24 regs quickly) ----
    float loc_diff2[4];
    {
        float L1[12], L2[12];
#pragma unroll
        for (int k = 0; k < 3; k++) {
            float4 a = l1p[k], b = l2p[k];
            L1[4 * k + 0] = a.x; L1[4 * k + 1] = a.y; L1[4 * k + 2] = a.z; L1[4 * k + 3] = a.w;
            L2[4 * k + 0] = b.x; L2[4 * k + 1] = b.y; L2[4 * k + 2] = b.z; L2[4 * k + 3] = b.w;
        }
#pragma unroll
        for (int g = 0; g < 4; g++) {
            float d0 = L1[3 * g + 0] - L2[3 * g + 0];
            float d1 = L1[3 * g + 1] - L2[3 * g + 1];
            float d2 = L1[3 * g + 2] - L2[3 * g + 2];
            loc_diff2[g] = d0 * d0 + d1 * d1 + d2 * d2;
        }
    }

    // ---- Phase B: cov2 (symmetric, 6 entries per g) + trace from side 2 ----
    float cov2[4][6];   // [g][{00,11,22,01,02,12}]
    float tr_cov2[4];
    {
        float S2[12], R2[36];
#pragma unroll
        for (int k = 0; k < 3; k++) {
            float4 v = s2p[k];
            S2[4 * k + 0] = v.x; S2[4 * k + 1] = v.y; S2[4 * k + 2] = v.z; S2[4 * k + 3] = v.w;
        }
#pragma unroll
        for (int k = 0; k < 9; k++) {
            float4 v = r2p[k];
            R2[4 * k + 0] = v.x; R2[4 * k + 1] = v.y; R2[4 * k + 2] = v.z; R2[4 * k + 3] = v.w;
        }
#pragma unroll
        for (int g = 0; g < 4; g++) {
            float s0 = fmaxf(S2[3 * g + 0], EPSF);
            float s1 = fmaxf(S2[3 * g + 1], EPSF);
            float s2 = fmaxf(S2[3 * g + 2], EPSF);
            const float* R = R2 + 9 * g;
            // cov2[r][c] = sum_j R[r][j]*s[j]*R[c][j]
            float c00 = R[0] * s0 * R[0] + R[1] * s1 * R[1] + R[2] * s2 * R[2];
            float c11 = R[3] * s0 * R[3] + R[4] * s1 * R[4] + R[5] * s2 * R[5];
            float c22 = R[6] * s0 * R[6] + R[7] * s1 * R[7] + R[8] * s2 * R[8];
            float c01 = R[0] * s0 * R[3] + R[1] * s1 * R[4] + R[2] * s2 * R[5];
            float c02 = R[0] * s0 * R[6] + R[1] * s1 * R[7] + R[2] * s2 * R[8];
            float c12 = R[3] * s0 * R[6] + R[4] * s1 * R[7] + R[5] * s2 * R[8];
            cov2[g][0] = c00; cov2[g][1] = c11; cov2[g][2] = c22;
            cov2[g][3] = c01; cov2[g][4] = c02; cov2[g][5] = c12;
            tr_cov2[g] = c00 + c11 + c22;
        }
    }

    // ---- Phase C: rotate into frame 1, scale by sqrt(s1), eigensolve ----
    float res[4];
    {
        float S1[12], R1[36];
#pragma unroll
        for (int k = 0; k < 3; k++) {
            float4 v = s1p[k];
            S1[4 * k + 0] = v.x; S1[4 * k + 1] = v.y; S1[4 * k + 2] = v.z; S1[4 * k + 3] = v.w;
        }
#pragma unroll
        for (int k = 0; k < 9; k++) {
            float4 v = r1p[k];
            R1[4 * k + 0] = v.x; R1[4 * k + 1] = v.y; R1[4 * k + 2] = v.z; R1[4 * k + 3] = v.w;
        }
#pragma unroll
        for (int g = 0; g < 4; g++) {
            float s0 = fmaxf(S1[3 * g + 0], EPSF);
            float s1 = fmaxf(S1[3 * g + 1], EPSF);
            float s2 = fmaxf(S1[3 * g + 2], EPSF);
            const float* R = R1 + 9 * g;
            // full cov2 matrix for this g
            float C[3][3];
            C[0][0] = cov2[g][0]; C[1][1] = cov2[g][1]; C[2][2] = cov2[g][2];
            C[0][1] = C[1][0] = cov2[g][3];
            C[0][2] = C[2][0] = cov2[g][4];
            C[1][2] = C[2][1] = cov2[g][5];

            // T = C * R1   (T[r][c] = sum_j C[r][j] * R[3j+c])
            float T[3][3];
#pragma unroll
            for (int r = 0; r < 3; r++)
#pragma unroll
                for (int c = 0; c < 3; c++)
                    T[r][c] = C[r][0] * R[c] + C[r][1] * R[3 + c] + C[r][2] * R[6 + c];

            // M = R1^T * T  (M[r][c] = sum_j R[3j+r] * T[j][c])
            float M[3][3];
#pragma unroll
            for (int r = 0; r < 3; r++)
#pragma unroll
                for (int c = 0; c < 3; c++)
                    M[r][c] = R[r] * T[0][c] + R[3 + r] * T[1][c] + R[6 + r] * T[2][c];

            float ss0 = sqrtf(s0), ss1 = sqrtf(s1), ss2 = sqrtf(s2);
            double a00 = (double)(s0 * M[0][0]) + 1e-8;
            double a11 = (double)(s1 * M[1][1]) + 1e-8;
            double a22 = (double)(s2 * M[2][2]) + 1e-8;
            double a01 = (double)(0.5f * (M[0][1] + M[1][0]) * ss0 * ss1);
            double a02 = (double)(0.5f * (M[0][2] + M[2][0]) * ss0 * ss2);
            double a12 = (double)(0.5f * (M[1][2] + M[2][1]) * ss1 * ss2);

            double trs = tr_sqrt_eig(a00, a11, a22, a01, a02, a12);

            float cov_w = (s0 + s1 + s2) + tr_cov2[g] - 2.0f * (float)trs;
            cov_w = fmaxf(cov_w, 0.0f);
            res[g] = sqrtf(fmaxf(loc_diff2[g] + cov_w, EPSF));
        }
    }

    float4 o;
    o.x = res[0]; o.y = res[1]; o.z = res[2]; o.w = res[3];
    ((float4*)out)[t] = o;
}

extern "C" void kernel_launch(void* const* d_in, const int* in_sizes, int n_in,
                              void* d_out, int out_size, void* d_ws, size_t ws_size,
                              hipStream_t stream) {
    const float* loc1   = (const float*)d_in[0];
    const float* scale1 = (const float*)d_in[1];
    const float* rot1   = (const float*)d_in[2];
    const float* loc2   = (const float*)d_in[3];
    const float* scale2 = (const float*)d_in[4];
    const float* rot2   = (const float*)d_in[5];
    float* out = (float*)d_out;

    int B = in_sizes[0] / 3;   // B == 1048576, divisible by 4
    int B4 = B / 4;
    int block = 256;
    int grid = (B4 + block - 1) / block;
    wasserstein_kernel<<<grid, block, 0, stream>>>(loc1, scale1, rot1, loc2, scale2, rot2, out, B4);
}